// Round 1
// baseline (93.461 us; speedup 1.0000x reference)
//
#include <hip/hip_runtime.h>

#define NEG_SLOPE_F 0.2f

static constexpr int Nn = 4096;   // nodes
static constexpr int Tt = 3;      // edge types
static constexpr int Dd = 16;     // emb dim
static constexpr int Hh = 4;      // heads

__device__ __forceinline__ float waveMax(float v) {
#pragma unroll
  for (int m = 1; m < 64; m <<= 1) v = fmaxf(v, __shfl_xor(v, m));
  return v;
}
__device__ __forceinline__ float waveSum(float v) {
#pragma unroll
  for (int m = 1; m < 64; m <<= 1) v += __shfl_xor(v, m);
  return v;
}

// ---- kernel 1: tiny prep: pv[0..11] = c[h][t], pv[12] = sum(scores) ----
__global__ void prep_kernel(const float* __restrict__ scores,
                            const float* __restrict__ emb,
                            const float* __restrict__ attw,
                            float* __restrict__ pv) {
  __shared__ float rb[4];
  int tid = threadIdx.x;  // 256 threads
  float s = 0.f;
  for (int j = tid; j < Nn; j += 256) s += scores[j];
  s = waveSum(s);
  if ((tid & 63) == 0) rb[tid >> 6] = s;
  __syncthreads();
  if (tid == 0) pv[12] = rb[0] + rb[1] + rb[2] + rb[3];
  if (tid < Hh * Tt) {
    int h = tid / Tt, t = tid % Tt;
    float c = 0.f;
#pragma unroll
    for (int d = 0; d < Dd; ++d) c += emb[t * Dd + d] * attw[h * (Dd + 2) + 1 + d];
    pv[tid] = c;
  }
}

// ---- kernel 2: build dense 3-bit adjacency mask via atomicOr (set semantics) ----
__global__ void build_mask_kernel(const int* __restrict__ el,
                                  unsigned int* __restrict__ maskw, int E) {
  int e = blockIdx.x * blockDim.x + threadIdx.x;
  int t = blockIdx.y;
  if (e >= E) return;
  unsigned int a = (unsigned int)el[(t * 2 + 0) * E + e];
  unsigned int b = (unsigned int)el[(t * 2 + 1) * E + e];
  unsigned int bit = 1u << t;
  unsigned int ia = a * Nn + b;
  unsigned int ib = b * Nn + a;
  atomicOr(&maskw[ia >> 2], bit << ((ia & 3u) * 8u));
  if (ib != ia) atomicOr(&maskw[ib >> 2], bit << ((ib & 3u) * 8u));
}

// ---- kernel 3: one block per row; sparse-aware softmax, all 4 heads ----
__launch_bounds__(256)
__global__ void row_kernel(const unsigned char* __restrict__ mask,
                           const float* __restrict__ scores,
                           const float* __restrict__ attw,
                           const float* __restrict__ pv,
                           float* __restrict__ out) {
  __shared__ unsigned char row[Nn];   // 4 KiB
  __shared__ float rb[16][4];
  int i = blockIdx.x;
  int tid = threadIdx.x;
  // stage the mask row: 256 threads * 16B = 4096B, coalesced
  ((uint4*)row)[tid] = ((const uint4*)(mask + (size_t)i * Nn))[tid];
  __syncthreads();

  float si = scores[i];
  float c0[Hh], c1[Hh], c2[Hh], wsrc[Hh], wtgt[Hh];
#pragma unroll
  for (int h = 0; h < Hh; ++h) {
    wsrc[h] = attw[h * (Dd + 2) + 0];
    wtgt[h] = attw[h * (Dd + 2) + Dd + 1];
    c0[h] = pv[h * 3 + 0];
    c1[h] = pv[h * 3 + 1];
    c2[h] = pv[h * 3 + 2];
  }
  float Ssum = pv[12];

  // ---- pass A: per-head max over edge logits; edge count; sum s_j over edges ----
  float mx[Hh];
#pragma unroll
  for (int h = 0; h < Hh; ++h) mx[h] = -INFINITY;
  float cntf = 0.f, ssum = 0.f;
  for (int j = tid; j < Nn; j += 256) {
    int m = row[j];
    if (m) {
      float sj = scores[j];
      cntf += 1.f;
      ssum += sj;
      float na = (float)__popc(m);
      float e0 = (m & 1) ? 1.f : 0.f;
      float e1 = (m & 2) ? 1.f : 0.f;
      float e2 = (m & 4) ? 1.f : 0.f;
#pragma unroll
      for (int h = 0; h < Hh; ++h) {
        float et = e0 * c0[h] + e1 * c1[h] + e2 * c2[h];
        float l = na * (wsrc[h] * si + wtgt[h] * sj) + et;
        l = (l >= 0.f) ? l : NEG_SLOPE_F * l;
        mx[h] = fmaxf(mx[h], l);
      }
    }
  }
  int wid = tid >> 6, lane = tid & 63;
#pragma unroll
  for (int h = 0; h < Hh; ++h) {
    float v = waveMax(mx[h]);
    if (lane == 0) rb[h][wid] = v;
  }
  {
    float v = waveSum(cntf);
    if (lane == 0) rb[4][wid] = v;
    v = waveSum(ssum);
    if (lane == 0) rb[5][wid] = v;
  }
  __syncthreads();
  float cnt = rb[4][0] + rb[4][1] + rb[4][2] + rb[4][3];
  float sedge = rb[5][0] + rb[5][1] + rb[5][2] + rb[5][3];
#pragma unroll
  for (int h = 0; h < Hh; ++h) {
    mx[h] = fmaxf(fmaxf(rb[h][0], rb[h][1]), fmaxf(rb[h][2], rb[h][3]));
    if (cnt < (float)Nn) mx[h] = fmaxf(mx[h], 0.f);  // non-edge logits are 0
  }

  // ---- pass B: exp sums over edges ----
  float se[Hh], ss[Hh];
#pragma unroll
  for (int h = 0; h < Hh; ++h) { se[h] = 0.f; ss[h] = 0.f; }
  for (int j = tid; j < Nn; j += 256) {
    int m = row[j];
    if (m) {
      float sj = scores[j];
      float na = (float)__popc(m);
      float e0 = (m & 1) ? 1.f : 0.f;
      float e1 = (m & 2) ? 1.f : 0.f;
      float e2 = (m & 4) ? 1.f : 0.f;
#pragma unroll
      for (int h = 0; h < Hh; ++h) {
        float et = e0 * c0[h] + e1 * c1[h] + e2 * c2[h];
        float l = na * (wsrc[h] * si + wtgt[h] * sj) + et;
        l = (l >= 0.f) ? l : NEG_SLOPE_F * l;
        float ex = expf(l - mx[h]);
        se[h] += ex;
        ss[h] += ex * sj;
      }
    }
  }
  __syncthreads();  // rb reuse barrier
#pragma unroll
  for (int h = 0; h < Hh; ++h) {
    float v = waveSum(se[h]);
    if (lane == 0) rb[h][wid] = v;
    v = waveSum(ss[h]);
    if (lane == 0) rb[8 + h][wid] = v;
  }
  __syncthreads();
  if (tid == 0) {
    float acc = 0.f;
#pragma unroll
    for (int h = 0; h < Hh; ++h) {
      float seh = rb[h][0] + rb[h][1] + rb[h][2] + rb[h][3];
      float ssh = rb[8 + h][0] + rb[8 + h][1] + rb[8 + h][2] + rb[8 + h][3];
      float nz = expf(-mx[h]);  // exp(0 - max): every non-edge cell
      float denom = seh + nz * ((float)Nn - cnt);
      float numer = ssh + nz * (Ssum - sedge);
      acc += numer / denom;
    }
    out[i] = acc * (1.f / (float)Hh);
  }
}

extern "C" void kernel_launch(void* const* d_in, const int* in_sizes, int n_in,
                              void* d_out, int out_size, void* d_ws, size_t ws_size,
                              hipStream_t stream) {
  const float* scores = (const float*)d_in[0];
  const float* emb    = (const float*)d_in[1];
  const float* attw   = (const float*)d_in[2];
  const int*   el     = (const int*)d_in[3];
  float* out = (float*)d_out;
  int E = in_sizes[3] / (Tt * 2);

  unsigned char* mask = (unsigned char*)d_ws;
  float* pv = (float*)((char*)d_ws + (size_t)Nn * Nn);

  hipMemsetAsync(d_ws, 0, (size_t)Nn * Nn, stream);
  prep_kernel<<<1, 256, 0, stream>>>(scores, emb, attw, pv);
  build_mask_kernel<<<dim3((E + 255) / 256, Tt), 256, 0, stream>>>(
      el, (unsigned int*)d_ws, E);
  row_kernel<<<Nn, 256, 0, stream>>>(mask, scores, attw, pv, out);
}

// Round 4
// 69.993 us; speedup vs baseline: 1.3353x; 1.3353x over previous
//
#include <hip/hip_runtime.h>

#define NEG_SLOPE_F 0.2f

static constexpr int Nn = 4096;   // nodes
static constexpr int Tt = 3;      // edge types
static constexpr int Dd = 16;     // emb dim
static constexpr int Hh = 4;      // heads
static constexpr int CAP = 256;   // max distinct neighbors per row (E[.]≈95, σ≈10 → huge headroom)

__device__ __forceinline__ float waveMax(float v) {
#pragma unroll
  for (int m = 1; m < 64; m <<= 1) v = fmaxf(v, __shfl_xor(v, m));
  return v;
}
__device__ __forceinline__ float waveSum(float v) {
#pragma unroll
  for (int m = 1; m < 64; m <<= 1) v += __shfl_xor(v, m);
  return v;
}

// ---- kernel 1: tiny prep: pv[0..11] = c[h][t], pv[12] = sum(scores) ----
__global__ void prep_kernel(const float* __restrict__ scores,
                            const float* __restrict__ emb,
                            const float* __restrict__ attw,
                            float* __restrict__ pv) {
  __shared__ float rb[4];
  int tid = threadIdx.x;  // 256 threads
  float s = 0.f;
  for (int j = tid; j < Nn; j += 256) s += scores[j];
  s = waveSum(s);
  if ((tid & 63) == 0) rb[tid >> 6] = s;
  __syncthreads();
  if (tid == 0) pv[12] = rb[0] + rb[1] + rb[2] + rb[3];
  if (tid < Hh * Tt) {
    int h = tid / Tt, t = tid % Tt;
    float c = 0.f;
#pragma unroll
    for (int d = 0; d < Dd; ++d) c += emb[t * Dd + d] * attw[h * (Dd + 2) + 1 + d];
    pv[tid] = c;
  }
}

// ---- kernel 2: dense 3-bit mask (set semantics) + first-setter CSR append ----
__global__ void build_kernel(const int* __restrict__ el,
                             unsigned int* __restrict__ maskw,
                             unsigned short* __restrict__ list,
                             unsigned int* __restrict__ cnt, int E) {
  int e = blockIdx.x * blockDim.x + threadIdx.x;
  int t = blockIdx.y;
  if (e >= E) return;
  unsigned int a = (unsigned int)el[(t * 2 + 0) * E + e];
  unsigned int b = (unsigned int)el[(t * 2 + 1) * E + e];
  unsigned int bit = 1u << t;
  {
    unsigned int idx = a * Nn + b;
    unsigned int sh = (idx & 3u) * 8u;
    unsigned int old = atomicOr(&maskw[idx >> 2], bit << sh);
    if (((old >> sh) & 0xffu) == 0u) {          // first bit ever in this cell
      unsigned int p = atomicAdd(&cnt[a], 1u);
      if (p < CAP) list[a * CAP + p] = (unsigned short)b;
    }
  }
  if (a != b) {
    unsigned int idx = b * Nn + a;
    unsigned int sh = (idx & 3u) * 8u;
    unsigned int old = atomicOr(&maskw[idx >> 2], bit << sh);
    if (((old >> sh) & 0xffu) == 0u) {
      unsigned int p = atomicAdd(&cnt[b], 1u);
      if (p < CAP) list[b * CAP + p] = (unsigned short)a;
    }
  }
}

// ---- kernel 3: one wave per row; dense processing of the row's edge list ----
__launch_bounds__(256)
__global__ void row_kernel(const unsigned char* __restrict__ mask,
                           const unsigned short* __restrict__ list,
                           const unsigned int* __restrict__ cnt,
                           const float* __restrict__ scores,
                           const float* __restrict__ attw,
                           const float* __restrict__ pv,
                           float* __restrict__ out) {
  int wid = threadIdx.x >> 6, lane = threadIdx.x & 63;
  int i = blockIdx.x * 4 + wid;
  int n = (int)cnt[i];                 // wave-uniform
  if (n > CAP) n = CAP;
  float si = scores[i];
  float wsrc[Hh], wtgt[Hh], c0[Hh], c1[Hh], c2[Hh];
#pragma unroll
  for (int h = 0; h < Hh; ++h) {
    wsrc[h] = attw[h * (Dd + 2) + 0];
    wtgt[h] = attw[h * (Dd + 2) + Dd + 1];
    c0[h] = pv[h * 3 + 0];
    c1[h] = pv[h * 3 + 1];
    c2[h] = pv[h * 3 + 2];
  }
  float Ssum = pv[12];

  constexpr int IT = CAP / 64;         // 4
  float lv[IT][Hh], sjv[IT];
  float mx[Hh];
#pragma unroll
  for (int h = 0; h < Hh; ++h) mx[h] = -INFINITY;
  float sedge = 0.f;

#pragma unroll
  for (int it = 0; it < IT; ++it) {
    if (it * 64 >= n) break;           // wave-uniform early-out
    int k = it * 64 + lane;
    bool act = k < n;
    int j = act ? (int)list[i * CAP + k] : 0;
    float sj = act ? scores[j] : 0.f;
    int m = act ? (int)mask[(size_t)i * Nn + j] : 0;
    sjv[it] = sj;
    if (act) sedge += sj;
    float na = (float)__popc(m);
    float et0 = (m & 1) ? 1.f : 0.f;
    float et1 = (m & 2) ? 1.f : 0.f;
    float et2 = (m & 4) ? 1.f : 0.f;
#pragma unroll
    for (int h = 0; h < Hh; ++h) {
      float et = et0 * c0[h] + et1 * c1[h] + et2 * c2[h];
      float l = na * (wsrc[h] * si + wtgt[h] * sj) + et;
      l = (l >= 0.f) ? l : NEG_SLOPE_F * l;
      lv[it][h] = act ? l : -INFINITY;
      mx[h] = fmaxf(mx[h], lv[it][h]);
    }
  }

#pragma unroll
  for (int h = 0; h < Hh; ++h) {
    mx[h] = waveMax(mx[h]);
    if (n < Nn) mx[h] = fmaxf(mx[h], 0.f);  // non-edge cells contribute logit 0
  }

  float se[Hh], ss[Hh];
#pragma unroll
  for (int h = 0; h < Hh; ++h) { se[h] = 0.f; ss[h] = 0.f; }
#pragma unroll
  for (int it = 0; it < IT; ++it) {
    if (it * 64 >= n) break;
#pragma unroll
    for (int h = 0; h < Hh; ++h) {
      float ex = expf(lv[it][h] - mx[h]);   // inactive lanes: exp(-inf)=0
      se[h] += ex;
      ss[h] += ex * sjv[it];
    }
  }
  sedge = waveSum(sedge);
#pragma unroll
  for (int h = 0; h < Hh; ++h) {
    se[h] = waveSum(se[h]);
    ss[h] = waveSum(ss[h]);
  }
  if (lane == 0) {
    float acc = 0.f;
#pragma unroll
    for (int h = 0; h < Hh; ++h) {
      float nz = expf(-mx[h]);              // exp(0 - max) for every non-edge cell
      float denom = se[h] + nz * ((float)Nn - (float)n);
      float numer = ss[h] + nz * (Ssum - sedge);
      acc += numer / denom;
    }
    out[i] = acc * (1.f / (float)Hh);
  }
}

extern "C" void kernel_launch(void* const* d_in, const int* in_sizes, int n_in,
                              void* d_out, int out_size, void* d_ws, size_t ws_size,
                              hipStream_t stream) {
  const float* scores = (const float*)d_in[0];
  const float* emb    = (const float*)d_in[1];
  const float* attw   = (const float*)d_in[2];
  const int*   el     = (const int*)d_in[3];
  float* out = (float*)d_out;
  int E = in_sizes[3] / (Tt * 2);

  // ws layout: [mask 16MB][cnt 16KB][pv 64B][list 2MB]
  unsigned char* mask = (unsigned char*)d_ws;
  unsigned int* cnt = (unsigned int*)((char*)d_ws + (size_t)Nn * Nn);
  float* pv = (float*)((char*)cnt + Nn * sizeof(unsigned int));
  unsigned short* list = (unsigned short*)((char*)pv + 64);

  // clear mask + cnt in one memset
  hipMemsetAsync(d_ws, 0, (size_t)Nn * Nn + Nn * sizeof(unsigned int), stream);
  prep_kernel<<<1, 256, 0, stream>>>(scores, emb, attw, pv);
  build_kernel<<<dim3((E + 255) / 256, Tt), 256, 0, stream>>>(
      el, (unsigned int*)d_ws, list, cnt, E);
  row_kernel<<<Nn / 4, 256, 0, stream>>>(mask, list, cnt, scores, attw, pv, out);
}

// Round 5
// 40.917 us; speedup vs baseline: 2.2842x; 1.7106x over previous
//
#include <hip/hip_runtime.h>

#define NEG_SLOPE_F 0.2f

static constexpr int Nn = 4096;   // nodes
static constexpr int Tt = 3;      // edge types
static constexpr int Dd = 16;     // emb dim
static constexpr int Hh = 4;      // heads
static constexpr int CAP = 256;   // max distinct neighbors per row (E[deg]≈96)
static constexpr int WPR = 128;   // 32-bit words per row per type (4096/32)

__device__ __forceinline__ float waveMax(float v) {
#pragma unroll
  for (int m = 1; m < 64; m <<= 1) v = fmaxf(v, __shfl_xor(v, m));
  return v;
}
__device__ __forceinline__ float waveSum(float v) {
#pragma unroll
  for (int m = 1; m < 64; m <<= 1) v += __shfl_xor(v, m);
  return v;
}

// ---- kernel 1: tiny prep: pv[0..11] = c[h][t], pv[12] = sum(scores) ----
__global__ void prep_kernel(const float* __restrict__ scores,
                            const float* __restrict__ emb,
                            const float* __restrict__ attw,
                            float* __restrict__ pv) {
  __shared__ float rb[4];
  int tid = threadIdx.x;  // 256 threads
  float s = 0.f;
  for (int j = tid; j < Nn; j += 256) s += scores[j];
  s = waveSum(s);
  if ((tid & 63) == 0) rb[tid >> 6] = s;
  __syncthreads();
  if (tid == 0) pv[12] = rb[0] + rb[1] + rb[2] + rb[3];
  if (tid < Hh * Tt) {
    int h = tid / Tt, t = tid % Tt;
    float c = 0.f;
#pragma unroll
    for (int d = 0; d < Dd; ++d) c += emb[t * Dd + d] * attw[h * (Dd + 2) + 1 + d];
    pv[tid] = c;
  }
}

// ---- kernel 2: fire-and-forget bit atomicOr into per-type bitmaps ----
// bitmap layout: word[(row*3 + t)*WPR + (col>>5)], bit = col&31
__global__ void or_kernel(const int* __restrict__ el,
                          unsigned int* __restrict__ bitmap, int E) {
  int e = blockIdx.x * blockDim.x + threadIdx.x;
  if (e >= E) return;
  int t = blockIdx.y;
  int dir = blockIdx.z;
  unsigned int a = (unsigned int)el[(t * 2 + dir) * E + e];
  unsigned int b = (unsigned int)el[(t * 2 + (1 - dir)) * E + e];
  atomicOr(&bitmap[(a * 3u + t) * WPR + (b >> 5)], 1u << (b & 31u));
}

// ---- kernel 3: atomic-free per-row compaction: bitmap -> packed (j|m<<12) list ----
__launch_bounds__(256)
__global__ void compact_kernel(const unsigned int* __restrict__ bitmap,
                               unsigned short* __restrict__ list,
                               unsigned int* __restrict__ cnt) {
  int wid = threadIdx.x >> 6, lane = threadIdx.x & 63;
  int row = blockIdx.x * 4 + wid;
  const unsigned int* bm = bitmap + (size_t)row * 3 * WPR;
  unsigned int w[2][3];
#pragma unroll
  for (int p = 0; p < 2; ++p)
#pragma unroll
    for (int t = 0; t < 3; ++t) w[p][t] = bm[t * WPR + p * 64 + lane];
  unsigned int orw[2];
  orw[0] = w[0][0] | w[0][1] | w[0][2];
  orw[1] = w[1][0] | w[1][1] | w[1][2];
  int c = __popc(orw[0]) + __popc(orw[1]);
  // inclusive wave scan
  int off = c;
#pragma unroll
  for (int d = 1; d < 64; d <<= 1) {
    int tv = __shfl_up(off, d);
    if (lane >= d) off += tv;
  }
  int total = __shfl(off, 63);
  off -= c;  // exclusive
  if (lane == 0) cnt[row] = (unsigned int)(total < CAP ? total : CAP);
  unsigned short* dst = list + (size_t)row * CAP;
  int idx = off;
#pragma unroll
  for (int p = 0; p < 2; ++p) {
    unsigned int o = orw[p];
    int jbase = (p * 64 + lane) * 32;
    while (o) {
      int b = __ffs(o) - 1;
      o &= o - 1;
      unsigned int m = ((w[p][0] >> b) & 1u) | (((w[p][1] >> b) & 1u) << 1) |
                       (((w[p][2] >> b) & 1u) << 2);
      if (idx < CAP) dst[idx] = (unsigned short)((jbase + b) | (m << 12));
      ++idx;
    }
  }
}

// ---- kernel 4: one wave per row; dense processing of the packed edge list ----
__launch_bounds__(256)
__global__ void row_kernel(const unsigned short* __restrict__ list,
                           const unsigned int* __restrict__ cnt,
                           const float* __restrict__ scores,
                           const float* __restrict__ attw,
                           const float* __restrict__ pv,
                           float* __restrict__ out) {
  int wid = threadIdx.x >> 6, lane = threadIdx.x & 63;
  int i = blockIdx.x * 4 + wid;
  int n = (int)cnt[i];                 // wave-uniform
  float si = scores[i];
  float wsrc[Hh], wtgt[Hh], c0[Hh], c1[Hh], c2[Hh];
#pragma unroll
  for (int h = 0; h < Hh; ++h) {
    wsrc[h] = attw[h * (Dd + 2) + 0];
    wtgt[h] = attw[h * (Dd + 2) + Dd + 1];
    c0[h] = pv[h * 3 + 0];
    c1[h] = pv[h * 3 + 1];
    c2[h] = pv[h * 3 + 2];
  }
  float Ssum = pv[12];

  constexpr int IT = CAP / 64;         // 4
  float lv[IT][Hh], sjv[IT];
  float mx[Hh];
#pragma unroll
  for (int h = 0; h < Hh; ++h) mx[h] = -INFINITY;
  float sedge = 0.f;

#pragma unroll
  for (int it = 0; it < IT; ++it) {
    if (it * 64 >= n) break;           // wave-uniform early-out
    int k = it * 64 + lane;
    bool act = k < n;
    unsigned int v = act ? (unsigned int)list[(size_t)i * CAP + k] : 0u;
    int j = (int)(v & 0xFFFu);
    int m = act ? (int)(v >> 12) : 0;
    float sj = act ? scores[j] : 0.f;
    sjv[it] = sj;
    if (act) sedge += sj;
    float na = (float)__popc(m);
    float et0 = (m & 1) ? 1.f : 0.f;
    float et1 = (m & 2) ? 1.f : 0.f;
    float et2 = (m & 4) ? 1.f : 0.f;
#pragma unroll
    for (int h = 0; h < Hh; ++h) {
      float et = et0 * c0[h] + et1 * c1[h] + et2 * c2[h];
      float l = na * (wsrc[h] * si + wtgt[h] * sj) + et;
      l = (l >= 0.f) ? l : NEG_SLOPE_F * l;
      lv[it][h] = act ? l : -INFINITY;
      mx[h] = fmaxf(mx[h], lv[it][h]);
    }
  }

#pragma unroll
  for (int h = 0; h < Hh; ++h) {
    mx[h] = waveMax(mx[h]);
    if (n < Nn) mx[h] = fmaxf(mx[h], 0.f);  // non-edge cells contribute logit 0
  }

  float se[Hh], ss[Hh];
#pragma unroll
  for (int h = 0; h < Hh; ++h) { se[h] = 0.f; ss[h] = 0.f; }
#pragma unroll
  for (int it = 0; it < IT; ++it) {
    if (it * 64 >= n) break;
#pragma unroll
    for (int h = 0; h < Hh; ++h) {
      float ex = expf(lv[it][h] - mx[h]);   // inactive lanes: exp(-inf)=0
      se[h] += ex;
      ss[h] += ex * sjv[it];
    }
  }
  sedge = waveSum(sedge);
#pragma unroll
  for (int h = 0; h < Hh; ++h) {
    se[h] = waveSum(se[h]);
    ss[h] = waveSum(ss[h]);
  }
  if (lane == 0) {
    float acc = 0.f;
#pragma unroll
    for (int h = 0; h < Hh; ++h) {
      float nz = expf(-mx[h]);              // exp(0 - max) for every non-edge cell
      float denom = se[h] + nz * ((float)Nn - (float)n);
      float numer = ss[h] + nz * (Ssum - sedge);
      acc += numer / denom;
    }
    out[i] = acc * (1.f / (float)Hh);
  }
}

extern "C" void kernel_launch(void* const* d_in, const int* in_sizes, int n_in,
                              void* d_out, int out_size, void* d_ws, size_t ws_size,
                              hipStream_t stream) {
  const float* scores = (const float*)d_in[0];
  const float* emb    = (const float*)d_in[1];
  const float* attw   = (const float*)d_in[2];
  const int*   el     = (const int*)d_in[3];
  float* out = (float*)d_out;
  int E = in_sizes[3] / (Tt * 2);

  // ws layout: [bitmap 6MB][cnt 16KB][pv 64B][list 2MB]
  size_t bm_bytes = (size_t)Nn * 3 * WPR * 4;     // 6 MiB
  unsigned int* bitmap = (unsigned int*)d_ws;
  unsigned int* cnt = (unsigned int*)((char*)d_ws + bm_bytes);
  float* pv = (float*)((char*)cnt + Nn * sizeof(unsigned int));
  unsigned short* list = (unsigned short*)((char*)pv + 64);

  hipMemsetAsync(d_ws, 0, bm_bytes + Nn * sizeof(unsigned int), stream);
  prep_kernel<<<1, 256, 0, stream>>>(scores, emb, attw, pv);
  or_kernel<<<dim3((E + 255) / 256, Tt, 2), 256, 0, stream>>>(el, bitmap, E);
  compact_kernel<<<Nn / 4, 256, 0, stream>>>(bitmap, list, cnt);
  row_kernel<<<Nn / 4, 256, 0, stream>>>(list, cnt, scores, attw, pv, out);
}

// Round 6
// 35.656 us; speedup vs baseline: 2.6212x; 1.1475x over previous
//
#include <hip/hip_runtime.h>

#define NEG_SLOPE_F 0.2f

static constexpr int Nn = 4096;   // nodes
static constexpr int Tt = 3;      // edge types
static constexpr int Dd = 16;     // emb dim
static constexpr int Hh = 4;      // heads
static constexpr int CAP = 256;   // max distinct neighbors per row (E[deg]≈96)
static constexpr int WPR = 128;   // 32-bit words per row per type (4096/32)

__device__ __forceinline__ float waveMax(float v) {
#pragma unroll
  for (int m = 1; m < 64; m <<= 1) v = fmaxf(v, __shfl_xor(v, m));
  return v;
}
__device__ __forceinline__ float waveSum(float v) {
#pragma unroll
  for (int m = 1; m < 64; m <<= 1) v += __shfl_xor(v, m);
  return v;
}

// ---- kernel 1: zero the 6 MB bitmap (wide grid-stride stores); block 0 also
// computes pv[0..11] = c[h][t] and pv[12] = sum(scores) ----
__global__ void clear_prep_kernel(uint4* __restrict__ bm4,
                                  const float* __restrict__ scores,
                                  const float* __restrict__ emb,
                                  const float* __restrict__ attw,
                                  float* __restrict__ pv) {
  const int total = Nn * 3 * WPR / 4;  // 393216 uint4
  uint4 z = make_uint4(0u, 0u, 0u, 0u);
  for (int k = blockIdx.x * 256 + threadIdx.x; k < total; k += gridDim.x * 256)
    bm4[k] = z;
  if (blockIdx.x == 0) {
    __shared__ float rb[4];
    int tid = threadIdx.x;
    float s = 0.f;
    for (int j = tid; j < Nn; j += 256) s += scores[j];
    s = waveSum(s);
    if ((tid & 63) == 0) rb[tid >> 6] = s;
    __syncthreads();
    if (tid == 0) pv[12] = rb[0] + rb[1] + rb[2] + rb[3];
    if (tid < Hh * Tt) {
      int h = tid / Tt, t = tid % Tt;
      float c = 0.f;
#pragma unroll
      for (int d = 0; d < Dd; ++d)
        c += emb[t * Dd + d] * attw[h * (Dd + 2) + 1 + d];
      pv[tid] = c;
    }
  }
}

// ---- kernel 2: fire-and-forget bit atomicOr, both directions per thread ----
// bitmap layout: word[(row*3 + t)*WPR + (col>>5)], bit = col&31
__global__ void or_kernel(const int* __restrict__ el,
                          unsigned int* __restrict__ bitmap, int E) {
  int e = blockIdx.x * blockDim.x + threadIdx.x;
  if (e >= E) return;
  int t = blockIdx.y;
  unsigned int a = (unsigned int)el[(t * 2 + 0) * E + e];
  unsigned int b = (unsigned int)el[(t * 2 + 1) * E + e];
  atomicOr(&bitmap[(a * 3u + t) * WPR + (b >> 5)], 1u << (b & 31u));
  atomicOr(&bitmap[(b * 3u + t) * WPR + (a >> 5)], 1u << (a & 31u));
}

// ---- kernel 3 (fused): one wave per row — extract (j, type-mask) pairs from
// the bitmap into an LDS list, then softmax-aggregate them immediately ----
__launch_bounds__(256)
__global__ void row_kernel(const unsigned int* __restrict__ bitmap,
                           const float* __restrict__ scores,
                           const float* __restrict__ attw,
                           const float* __restrict__ pv,
                           float* __restrict__ out) {
  __shared__ unsigned short lst[4][CAP];  // 2 KiB
  int wid = threadIdx.x >> 6, lane = threadIdx.x & 63;
  int i = blockIdx.x * 4 + wid;
  const unsigned int* bm = bitmap + (size_t)i * 3 * WPR;

  // read this row's 6 words per lane (2 word-blocks x 3 types), coalesced
  unsigned int w[2][3];
#pragma unroll
  for (int p = 0; p < 2; ++p)
#pragma unroll
    for (int t = 0; t < 3; ++t) w[p][t] = bm[t * WPR + p * 64 + lane];
  unsigned int orw[2];
  orw[0] = w[0][0] | w[0][1] | w[0][2];
  orw[1] = w[1][0] | w[1][1] | w[1][2];
  int c = __popc(orw[0]) + __popc(orw[1]);
  // inclusive wave scan -> per-lane output offsets
  int off = c;
#pragma unroll
  for (int d = 1; d < 64; d <<= 1) {
    int tv = __shfl_up(off, d);
    if (lane >= d) off += tv;
  }
  int n = __shfl(off, 63);  // row degree (distinct neighbors)
  off -= c;                 // exclusive
  if (n > CAP) n = CAP;
  int idx = off;
#pragma unroll
  for (int p = 0; p < 2; ++p) {
    unsigned int o = orw[p];
    int jbase = (p * 64 + lane) * 32;
    while (o) {
      int b = __ffs(o) - 1;
      o &= o - 1;
      unsigned int m = ((w[p][0] >> b) & 1u) | (((w[p][1] >> b) & 1u) << 1) |
                       (((w[p][2] >> b) & 1u) << 2);
      if (idx < CAP) lst[wid][idx] = (unsigned short)((jbase + b) | (m << 12));
      ++idx;
    }
  }
  __syncthreads();  // LDS write->read visibility

  float si = scores[i];
  float wsrc[Hh], wtgt[Hh], c0[Hh], c1[Hh], c2[Hh];
#pragma unroll
  for (int h = 0; h < Hh; ++h) {
    wsrc[h] = attw[h * (Dd + 2) + 0];
    wtgt[h] = attw[h * (Dd + 2) + Dd + 1];
    c0[h] = pv[h * 3 + 0];
    c1[h] = pv[h * 3 + 1];
    c2[h] = pv[h * 3 + 2];
  }
  float Ssum = pv[12];

  constexpr int IT = CAP / 64;  // 4
  float lv[IT][Hh], sjv[IT];
  float mx[Hh];
#pragma unroll
  for (int h = 0; h < Hh; ++h) mx[h] = -INFINITY;
  float sedge = 0.f;

#pragma unroll
  for (int it = 0; it < IT; ++it) {
    if (it * 64 >= n) break;  // wave-uniform early-out
    int k = it * 64 + lane;
    bool act = k < n;
    unsigned int v = act ? (unsigned int)lst[wid][k] : 0u;
    int j = (int)(v & 0xFFFu);
    int m = act ? (int)(v >> 12) : 0;
    float sj = act ? scores[j] : 0.f;
    sjv[it] = sj;
    if (act) sedge += sj;
    float na = (float)__popc(m);
    float et0 = (m & 1) ? 1.f : 0.f;
    float et1 = (m & 2) ? 1.f : 0.f;
    float et2 = (m & 4) ? 1.f : 0.f;
#pragma unroll
    for (int h = 0; h < Hh; ++h) {
      float et = et0 * c0[h] + et1 * c1[h] + et2 * c2[h];
      float l = na * (wsrc[h] * si + wtgt[h] * sj) + et;
      l = (l >= 0.f) ? l : NEG_SLOPE_F * l;
      lv[it][h] = act ? l : -INFINITY;
      mx[h] = fmaxf(mx[h], lv[it][h]);
    }
  }

#pragma unroll
  for (int h = 0; h < Hh; ++h) {
    mx[h] = waveMax(mx[h]);
    if (n < Nn) mx[h] = fmaxf(mx[h], 0.f);  // non-edge cells contribute logit 0
  }

  float se[Hh], ss[Hh];
#pragma unroll
  for (int h = 0; h < Hh; ++h) { se[h] = 0.f; ss[h] = 0.f; }
#pragma unroll
  for (int it = 0; it < IT; ++it) {
    if (it * 64 >= n) break;
#pragma unroll
    for (int h = 0; h < Hh; ++h) {
      float ex = expf(lv[it][h] - mx[h]);  // inactive lanes: exp(-inf)=0
      se[h] += ex;
      ss[h] += ex * sjv[it];
    }
  }
  sedge = waveSum(sedge);
#pragma unroll
  for (int h = 0; h < Hh; ++h) {
    se[h] = waveSum(se[h]);
    ss[h] = waveSum(ss[h]);
  }
  if (lane == 0) {
    float acc = 0.f;
#pragma unroll
    for (int h = 0; h < Hh; ++h) {
      float nz = expf(-mx[h]);  // exp(0 - max) for every non-edge cell
      float denom = se[h] + nz * ((float)Nn - (float)n);
      float numer = ss[h] + nz * (Ssum - sedge);
      acc += numer / denom;
    }
    out[i] = acc * (1.f / (float)Hh);
  }
}

extern "C" void kernel_launch(void* const* d_in, const int* in_sizes, int n_in,
                              void* d_out, int out_size, void* d_ws, size_t ws_size,
                              hipStream_t stream) {
  const float* scores = (const float*)d_in[0];
  const float* emb    = (const float*)d_in[1];
  const float* attw   = (const float*)d_in[2];
  const int*   el     = (const int*)d_in[3];
  float* out = (float*)d_out;
  int E = in_sizes[3] / (Tt * 2);

  // ws layout: [bitmap 6MB][pv 64B]
  size_t bm_bytes = (size_t)Nn * 3 * WPR * 4;  // 6 MiB
  unsigned int* bitmap = (unsigned int*)d_ws;
  float* pv = (float*)((char*)d_ws + bm_bytes);

  clear_prep_kernel<<<768, 256, 0, stream>>>((uint4*)d_ws, scores, emb, attw, pv);
  or_kernel<<<dim3((E + 255) / 256, Tt), 256, 0, stream>>>(el, bitmap, E);
  row_kernel<<<Nn / 4, 256, 0, stream>>>(bitmap, scores, attw, pv, out);
}